// Round 5
// baseline (220.429 us; speedup 1.0000x reference)
//
#include <hip/hip_runtime.h>
#include <hip/hip_bf16.h>
#include <math.h>

#define N_PTS 200000
#define M 32
#define P_INST 64
#define D 16
#define NP 337

#define LPB 128                        // points per layer block
#define NBL ((N_PTS + LPB - 1) / LPB)  // 1563
#define HPB 128                        // points per head block
#define NBH ((N_PTS + HPB - 1) / HPB)  // 1563

// ws float-offset layout:
#define WS_PARAMS 0         // 64*337 = 21568
#define WS_STATS  21568     // 3*64 (per layer: a[32], c[32])
#define WS_W2     21760     // 64*16
#define WS_B2     22784     // 64
#define WS_APACK  22912     // 64*512 bf16 = 16384 float-slots
#define WS_Y      104832    // 200000*32 floats (25.6MB)
// partials[NBL][64] lives in d_out (scratch until k_head overwrites it)

typedef __attribute__((ext_vector_type(8))) short short8v;
typedef __attribute__((ext_vector_type(4))) float floatx4;

static __device__ __forceinline__ unsigned short f2bf(float v) {
    __hip_bfloat16 h = __float2bfloat16(v);
    return *reinterpret_cast<unsigned short*>(&h);
}

// ---------------------------------------------------------------------------
// k_params: embedding MLP + BN(64) + controller -> params (one tiny block)
// ---------------------------------------------------------------------------
__global__ __launch_bounds__(256) void k_params(
    const float* __restrict__ inst, const float* __restrict__ emb_w,
    const float* __restrict__ emb_g, const float* __restrict__ emb_b,
    const float* __restrict__ ctrl_w, const float* __restrict__ ctrl_b,
    float* __restrict__ params)
{
    __shared__ float sInst[P_INST * M];
    __shared__ float sE[P_INST * D];
    __shared__ float sCW[D * NP];
    __shared__ float sA[D], sC[D];
    int t = threadIdx.x;

    for (int i = t; i < P_INST * M; i += 256) sInst[i] = inst[i];
    for (int i = t; i < D * NP; i += 256) sCW[i] = ctrl_w[i];
    __syncthreads();

    for (int i = t; i < P_INST * D; i += 256) {
        int p = i >> 4, d = i & (D - 1);
        float acc = 0.f;
        #pragma unroll
        for (int k = 0; k < M; k++) acc = fmaf(sInst[p * M + k], emb_w[k * D + d], acc);
        sE[i] = acc;
    }
    __syncthreads();

    if (t < D) {
        float s = 0.f, q = 0.f;
        for (int p = 0; p < P_INST; p++) { float v = sE[p * D + t]; s += v; q += v * v; }
        float mu = s * (1.f / P_INST);
        float var = q * (1.f / P_INST) - mu * mu;
        float a = emb_g[t] * rsqrtf(var + 1e-5f);
        sA[t] = a;
        sC[t] = emb_b[t] - mu * a;
    }
    __syncthreads();

    for (int i = t; i < P_INST * D; i += 256) {
        int d = i & (D - 1);
        sE[i] = fmaxf(sE[i] * sA[d] + sC[d], 0.f);
    }
    __syncthreads();

    for (int i = t; i < P_INST * NP; i += 256) {
        int p = i / NP, q = i - p * NP;
        float acc = ctrl_b[q];
        #pragma unroll
        for (int d = 0; d < D; d++) acc = fmaf(sE[p * D + d], sCW[d * NP + q], acc);
        params[i] = acc;
    }
}

// ---------------------------------------------------------------------------
// k_pack: one block per p — A-frag pack (bf16, centers folded), w2, b2
// ---------------------------------------------------------------------------
__global__ __launch_bounds__(64) void k_pack(
    const float* __restrict__ params, const float* __restrict__ centers,
    float* __restrict__ apackf, float* __restrict__ w2p, float* __restrict__ b2p)
{
    int p = blockIdx.x;
    int l = threadIdx.x;
    const float* pp = params + p * NP;
    int row = l & 15, kbase = (l >> 4) * 8;

    unsigned int w[4];
    #pragma unroll
    for (int i = 0; i < 4; i++) {
        unsigned short lo = 0, hi = 0;
        #pragma unroll
        for (int h = 0; h < 2; h++) {
            int k = kbase + 2 * i + h;
            float v;
            if (k < 19) v = pp[row * 19 + k];
            else if (k == 19)
                v = pp[320 + row] - (centers[p * 3 + 0] * pp[row * 19 + 0]
                                   + centers[p * 3 + 1] * pp[row * 19 + 1]
                                   + centers[p * 3 + 2] * pp[row * 19 + 2]);
            else v = 0.f;
            if (h == 0) lo = f2bf(v); else hi = f2bf(v);
        }
        w[i] = (unsigned)lo | ((unsigned)hi << 16);
    }
    uint4* dst = (uint4*)((char*)apackf + (size_t)p * 1024 + l * 16);
    *dst = make_uint4(w[0], w[1], w[2], w[3]);

    if (l < 16) w2p[p * 16 + l] = pp[304 + l];
    if (l == 0) b2p[p] = pp[336];
}

// ---------------------------------------------------------------------------
// One MLP layer + fused stats. 128 pts/block, 4 waves:
// wave = (slab = wv>>1 selects 64-pt group, chalf = wv&1 selects 16 out-chs).
// W indexed wave-uniformly -> s_load.
// ---------------------------------------------------------------------------
template <int L>
__global__ __launch_bounds__(256) void k_layer(
    const float* __restrict__ feats, const float* __restrict__ W,
    const float* __restrict__ stats, float* __restrict__ ybuf,
    float* __restrict__ partials)
{
    __shared__ float tr[LPB * 33];
    __shared__ float red2[2][8][32];
    int t = threadIdx.x;
    int lane = t & 63, wv = t >> 6;
    int slab = wv >> 1, ch = (wv & 1) * 16;
    int row = blockIdx.x * LPB + slab * 64 + lane;
    bool valid = row < N_PTS;
    int nc = valid ? row : N_PTS - 1;

    const float* src = ((L == 0) ? feats : ybuf) + (size_t)nc * M;
    float x[M];
    #pragma unroll
    for (int q = 0; q < M / 4; q++) {
        float4 v = ((const float4*)src)[q];
        x[4*q] = v.x; x[4*q+1] = v.y; x[4*q+2] = v.z; x[4*q+3] = v.w;
    }
    if (L > 0) {
        const float* st = stats + (L - 1) * 64;
        #pragma unroll
        for (int j = 0; j < M; j++) x[j] = fmaxf(fmaf(x[j], st[j], st[32 + j]), 0.f);
    }
    float y[16];
    #pragma unroll
    for (int j = 0; j < 16; j++) y[j] = 0.f;
    #pragma unroll
    for (int i = 0; i < M; i++) {
        float xi = x[i];
        #pragma unroll
        for (int j = 0; j < 16; j++) y[j] = fmaf(xi, W[i * M + ch + j], y[j]);
    }
    if (valid) {
        float4* dst = (float4*)(ybuf + (size_t)row * M + ch);
        #pragma unroll
        for (int q = 0; q < 4; q++)
            dst[q] = make_float4(y[4*q], y[4*q+1], y[4*q+2], y[4*q+3]);
    } else {
        #pragma unroll
        for (int j = 0; j < 16; j++) y[j] = 0.f;
    }

    // block reduction
    int r = slab * 64 + lane;
    #pragma unroll
    for (int j = 0; j < 16; j++) tr[r * 33 + ch + j] = y[j];
    __syncthreads();
    int c = t & 31, s = t >> 5;
    float S = 0.f, Q = 0.f;
    #pragma unroll
    for (int k = 0; k < 16; k++) {
        float v = tr[(s * 16 + k) * 33 + c];
        S += v; Q += v * v;
    }
    red2[0][s][c] = S;
    red2[1][s][c] = Q;
    __syncthreads();
    if (t < 64) {
        int cc = t & 31, k = t >> 5;
        float a = 0.f;
        #pragma unroll
        for (int sl = 0; sl < 8; sl++) a += red2[k][sl][cc];
        partials[(size_t)blockIdx.x * 64 + k * 32 + cc] = a;
    }
}

// ---------------------------------------------------------------------------
// Parallel reduce: block c handles channel c
// ---------------------------------------------------------------------------
__global__ __launch_bounds__(256) void k_reduce(
    const float* __restrict__ partials,
    const float* __restrict__ g, const float* __restrict__ b,
    float* __restrict__ stats_out)
{
    int c = blockIdx.x;
    int t = threadIdx.x;
    int part = t >> 7;
    int i0 = t & 127;
    float s = 0.f;
    for (int i = i0; i < NBL; i += 128)
        s += partials[(size_t)i * 64 + part * 32 + c];
    __shared__ float sh[256];
    sh[t] = s;
    __syncthreads();
    #pragma unroll
    for (int off = 64; off; off >>= 1) {
        if ((t & 127) < off) sh[t] += sh[t + off];
        __syncthreads();
    }
    if (t == 0) {
        float S = sh[0], Q = sh[128];
        float mu = S * (1.f / N_PTS);
        float var = Q * (1.f / N_PTS) - mu * mu;
        float a = g[c] * rsqrtf(var + 1e-5f);
        stats_out[c] = a;
        stats_out[32 + c] = b[c] - mu * a;
    }
}

// ---------------------------------------------------------------------------
// Fused head. 512 threads = 8 waves; 128 points.
// wave: slab = wv&1 (64-pt group), pq = wv>>1 (16 p's). 16 iters/wave.
// ---------------------------------------------------------------------------
__global__ __launch_bounds__(512) void k_head(
    const float* __restrict__ ybuf, const float* __restrict__ coords,
    const float* __restrict__ w_out, const float* __restrict__ b_out,
    const float* __restrict__ stats, const float* __restrict__ w2p,
    const float* __restrict__ b2p, const float* __restrict__ apackf,
    float* __restrict__ out)
{
    __shared__ unsigned int zlds[HPB * 20];
    int t = threadIdx.x;
    int nblk = blockIdx.x * HPB;

    if (t < HPB) {
        int nc = nblk + t;
        if (nc >= N_PTS) nc = N_PTS - 1;
        const float* yr = ybuf + (size_t)nc * M;
        float x[M];
        #pragma unroll
        for (int q = 0; q < M / 4; q++) {
            float4 v = ((const float4*)yr)[q];
            x[4*q] = v.x; x[4*q+1] = v.y; x[4*q+2] = v.z; x[4*q+3] = v.w;
        }
        const float* st = stats + 128;
        #pragma unroll
        for (int j = 0; j < M; j++) x[j] = fmaxf(fmaf(x[j], st[j], st[32 + j]), 0.f);

        float mf[D];
        #pragma unroll
        for (int d = 0; d < D; d++) mf[d] = b_out[d];
        #pragma unroll
        for (int i = 0; i < M; i++) {
            float xi = x[i];
            #pragma unroll
            for (int d = 0; d < D; d++) mf[d] = fmaf(xi, w_out[i * D + d], mf[d]);
        }
        float z[20];
        z[0] = coords[(size_t)nc * 3 + 0];
        z[1] = coords[(size_t)nc * 3 + 1];
        z[2] = coords[(size_t)nc * 3 + 2];
        #pragma unroll
        for (int d = 0; d < D; d++) z[3 + d] = mf[d];
        z[19] = 1.0f;

        unsigned int zw[16];
        #pragma unroll
        for (int i = 0; i < 10; i++)
            zw[i] = (unsigned)f2bf(z[2 * i]) | ((unsigned)f2bf(z[2 * i + 1]) << 16);
        #pragma unroll
        for (int i = 10; i < 16; i++) zw[i] = 0u;
        uint4* zd = (uint4*)&zlds[t * 20];
        #pragma unroll
        for (int i = 0; i < 4; i++)
            zd[i] = make_uint4(zw[4*i], zw[4*i+1], zw[4*i+2], zw[4*i+3]);
    }
    __syncthreads();

    int lane = t & 63, wv = t >> 6;
    int slab = wv & 1, pq = wv >> 1;      // pq in 0..3 -> p = pq*16 + i
    int cl = lane & 15, kg = lane >> 4;
    int n0 = nblk + slab * 64;
    int nn = n0 + lane;
    bool wr = nn < N_PTS;

    short8v b8[4];
    #pragma unroll
    for (int s = 0; s < 4; s++)
        b8[s] = *(const short8v*)&zlds[(slab * 64 + s * 16 + cl) * 20 + kg * 4];

    const char* abase = (const char*)apackf + (size_t)(pq * 16) * 1024 + lane * 16;
    float* outb = out + (size_t)(pq * 16) * N_PTS + nn;

    #pragma unroll 4
    for (int i = 0; i < 16; i++) {
        int p = pq * 16 + i;
        short8v a8 = *(const short8v*)(abase + (size_t)i * 1024);
        floatx4 w2v = *(const floatx4*)(w2p + p * 16 + kg * 4);
        float b2 = b2p[p];

        float vs[4];
        #pragma unroll
        for (int s = 0; s < 4; s++) {
            floatx4 acc = {0.f, 0.f, 0.f, 0.f};
            acc = __builtin_amdgcn_mfma_f32_16x16x32_bf16(a8, b8[s], acc, 0, 0, 0);
            float v = fmaxf(acc[0], 0.f) * w2v[0];
            v = fmaf(fmaxf(acc[1], 0.f), w2v[1], v);
            v = fmaf(fmaxf(acc[2], 0.f), w2v[2], v);
            v = fmaf(fmaxf(acc[3], 0.f), w2v[3], v);
            v += __shfl_xor(v, 16, 64);
            v += __shfl_xor(v, 32, 64);
            vs[s] = v;
        }
        float vout = (kg == 0) ? vs[0] : (kg == 1) ? vs[1] : (kg == 2) ? vs[2] : vs[3];
        if (wr) outb[(size_t)i * N_PTS] = vout + b2;
    }
}

// ---------------------------------------------------------------------------
extern "C" void kernel_launch(void* const* d_in, const int* in_sizes, int n_in,
                              void* d_out, int out_size, void* d_ws, size_t ws_size,
                              hipStream_t stream) {
    const float* feats   = (const float*)d_in[0];
    const float* coords  = (const float*)d_in[1];
    const float* inst    = (const float*)d_in[2];
    const float* centers = (const float*)d_in[3];
    const float* mw1 = (const float*)d_in[4];
    const float* mg1 = (const float*)d_in[5];
    const float* mb1 = (const float*)d_in[6];
    const float* mw2 = (const float*)d_in[7];
    const float* mg2 = (const float*)d_in[8];
    const float* mb2 = (const float*)d_in[9];
    const float* mw3 = (const float*)d_in[10];
    const float* mg3 = (const float*)d_in[11];
    const float* mb3 = (const float*)d_in[12];
    const float* wout = (const float*)d_in[13];
    const float* bout = (const float*)d_in[14];
    const float* embw = (const float*)d_in[15];
    const float* embg = (const float*)d_in[16];
    const float* embb = (const float*)d_in[17];
    const float* cw   = (const float*)d_in[18];
    const float* cb   = (const float*)d_in[19];

    float* wsf      = (float*)d_ws;
    float* params   = wsf + WS_PARAMS;
    float* stats    = wsf + WS_STATS;
    float* w2p      = wsf + WS_W2;
    float* b2p      = wsf + WS_B2;
    float* apackf   = wsf + WS_APACK;
    float* ybuf     = wsf + WS_Y;
    float* out      = (float*)d_out;
    float* partials = (float*)d_out;   // scratch until k_head overwrites out

    k_params<<<1, 256, 0, stream>>>(inst, embw, embg, embb, cw, cb, params);
    k_pack<<<P_INST, 64, 0, stream>>>(params, centers, apackf, w2p, b2p);

    k_layer<0><<<NBL, 256, 0, stream>>>(feats, mw1, stats, ybuf, partials);
    k_reduce<<<32, 256, 0, stream>>>(partials, mg1, mb1, stats + 0);

    k_layer<1><<<NBL, 256, 0, stream>>>(feats, mw2, stats, ybuf, partials);
    k_reduce<<<32, 256, 0, stream>>>(partials, mg2, mb2, stats + 64);

    k_layer<2><<<NBL, 256, 0, stream>>>(feats, mw3, stats, ybuf, partials);
    k_reduce<<<32, 256, 0, stream>>>(partials, mg3, mb3, stats + 128);

    k_head<<<NBH, 512, 0, stream>>>(ybuf, coords, wout, bout, stats,
                                    w2p, b2p, apackf, out);
}

// Round 6
// 190.584 us; speedup vs baseline: 1.1566x; 1.1566x over previous
//
#include <hip/hip_runtime.h>
#include <hip/hip_bf16.h>
#include <math.h>

#define N_PTS 200000
#define M 32
#define P_INST 64
#define D 16
#define NP 337

#define NBL ((N_PTS + 255) / 256)      // 782 layer blocks (256 pts each)
#define HPB 128                        // points per head block
#define NBH ((N_PTS + HPB - 1) / HPB)  // 1563
#define COLS_BLOCKS 2048               // colsum grid

// ws float-offset layout:
#define WS_PARAMS 0         // 64*337 = 21568
#define WS_STATS  21568     // 3*64 (per layer: a[32], c[32])
#define WS_W2     21760     // 64*16
#define WS_B2     22784     // 64
#define WS_APACK  22912     // 64*512 bf16 = 16384 float-slots
#define WS_Y      104832    // 200000*32 floats (25.6MB)
// partials[COLS_BLOCKS][64] live in d_out (scratch until k_head overwrites)

typedef __attribute__((ext_vector_type(8))) short short8v;
typedef __attribute__((ext_vector_type(4))) float floatx4;

static __device__ __forceinline__ unsigned short f2bf(float v) {
    __hip_bfloat16 h = __float2bfloat16(v);
    return *reinterpret_cast<unsigned short*>(&h);
}

// ---------------------------------------------------------------------------
// k_params: embedding MLP + BN(64) + controller -> params (one tiny block)
// ---------------------------------------------------------------------------
__global__ __launch_bounds__(256) void k_params(
    const float* __restrict__ inst, const float* __restrict__ emb_w,
    const float* __restrict__ emb_g, const float* __restrict__ emb_b,
    const float* __restrict__ ctrl_w, const float* __restrict__ ctrl_b,
    float* __restrict__ params)
{
    __shared__ float sInst[P_INST * M];
    __shared__ float sE[P_INST * D];
    __shared__ float sCW[D * NP];
    __shared__ float sA[D], sC[D];
    int t = threadIdx.x;

    for (int i = t; i < P_INST * M; i += 256) sInst[i] = inst[i];
    for (int i = t; i < D * NP; i += 256) sCW[i] = ctrl_w[i];
    __syncthreads();

    for (int i = t; i < P_INST * D; i += 256) {
        int p = i >> 4, d = i & (D - 1);
        float acc = 0.f;
        #pragma unroll
        for (int k = 0; k < M; k++) acc = fmaf(sInst[p * M + k], emb_w[k * D + d], acc);
        sE[i] = acc;
    }
    __syncthreads();

    if (t < D) {
        float s = 0.f, q = 0.f;
        for (int p = 0; p < P_INST; p++) { float v = sE[p * D + t]; s += v; q += v * v; }
        float mu = s * (1.f / P_INST);
        float var = q * (1.f / P_INST) - mu * mu;
        float a = emb_g[t] * rsqrtf(var + 1e-5f);
        sA[t] = a;
        sC[t] = emb_b[t] - mu * a;
    }
    __syncthreads();

    for (int i = t; i < P_INST * D; i += 256) {
        int d = i & (D - 1);
        sE[i] = fmaxf(sE[i] * sA[d] + sC[d], 0.f);
    }
    __syncthreads();

    for (int i = t; i < P_INST * NP; i += 256) {
        int p = i / NP, q = i - p * NP;
        float acc = ctrl_b[q];
        #pragma unroll
        for (int d = 0; d < D; d++) acc = fmaf(sE[p * D + d], sCW[d * NP + q], acc);
        params[i] = acc;
    }
}

// ---------------------------------------------------------------------------
// k_pack: one block per p — A-frag pack (bf16, centers folded), w2, b2
// ---------------------------------------------------------------------------
__global__ __launch_bounds__(64) void k_pack(
    const float* __restrict__ params, const float* __restrict__ centers,
    float* __restrict__ apackf, float* __restrict__ w2p, float* __restrict__ b2p)
{
    int p = blockIdx.x;
    int l = threadIdx.x;
    const float* pp = params + p * NP;
    int row = l & 15, kbase = (l >> 4) * 8;

    unsigned int w[4];
    #pragma unroll
    for (int i = 0; i < 4; i++) {
        unsigned short lo = 0, hi = 0;
        #pragma unroll
        for (int h = 0; h < 2; h++) {
            int k = kbase + 2 * i + h;
            float v;
            if (k < 19) v = pp[row * 19 + k];
            else if (k == 19)
                v = pp[320 + row] - (centers[p * 3 + 0] * pp[row * 19 + 0]
                                   + centers[p * 3 + 1] * pp[row * 19 + 1]
                                   + centers[p * 3 + 2] * pp[row * 19 + 2]);
            else v = 0.f;
            if (h == 0) lo = f2bf(v); else hi = f2bf(v);
        }
        w[i] = (unsigned)lo | ((unsigned)hi << 16);
    }
    uint4* dst = (uint4*)((char*)apackf + (size_t)p * 1024 + l * 16);
    *dst = make_uint4(w[0], w[1], w[2], w[3]);

    if (l < 16) w2p[p * 16 + l] = pp[304 + l];
    if (l == 0) b2p[p] = pp[336];
}

// ---------------------------------------------------------------------------
// Pure streaming layer: (optional BN+relu of prev) then x @ W -> ybuf.
// No LDS, no barriers. All W/stat indices compile-time -> s_load.
// ---------------------------------------------------------------------------
template <int L>
__global__ __launch_bounds__(256) void k_layer(
    const float* __restrict__ feats, const float* __restrict__ W,
    const float* __restrict__ stats, float* __restrict__ ybuf)
{
    int n = blockIdx.x * 256 + threadIdx.x;
    if (n >= N_PTS) return;

    const float* src = ((L == 0) ? feats : ybuf) + (size_t)n * M;
    float x[M];
    #pragma unroll
    for (int q = 0; q < M / 4; q++) {
        float4 v = ((const float4*)src)[q];
        x[4*q] = v.x; x[4*q+1] = v.y; x[4*q+2] = v.z; x[4*q+3] = v.w;
    }
    if (L > 0) {
        const float* st = stats + (L - 1) * 64;
        #pragma unroll
        for (int j = 0; j < M; j++) x[j] = fmaxf(fmaf(x[j], st[j], st[32 + j]), 0.f);
    }
    float y[M];
    #pragma unroll
    for (int j = 0; j < M; j++) y[j] = 0.f;
    #pragma unroll
    for (int i = 0; i < M; i++) {
        float xi = x[i];
        #pragma unroll
        for (int j = 0; j < M; j++) y[j] = fmaf(xi, W[i * M + j], y[j]);
    }
    float4* dst = (float4*)(ybuf + (size_t)n * M);
    #pragma unroll
    for (int q = 0; q < M / 4; q++)
        dst[q] = make_float4(y[4*q], y[4*q+1], y[4*q+2], y[4*q+3]);
}

// ---------------------------------------------------------------------------
// BW-bound column sums of ybuf -> partials[bid][j] (j<32: sum, j>=32: sumsq)
// ---------------------------------------------------------------------------
__global__ __launch_bounds__(256) void k_colsum(
    const float* __restrict__ ybuf, float* __restrict__ partials)
{
    int t = threadIdx.x;
    int g = t & 7;
    float s[4] = {0.f, 0.f, 0.f, 0.f}, q[4] = {0.f, 0.f, 0.f, 0.f};

    for (size_t idx = (size_t)blockIdx.x * 256 + t; idx < (size_t)N_PTS * 8;
         idx += (size_t)COLS_BLOCKS * 256) {
        size_t row = idx >> 3;
        float4 v = *(const float4*)(ybuf + row * M + g * 4);
        s[0] += v.x; s[1] += v.y; s[2] += v.z; s[3] += v.w;
        q[0] += v.x * v.x; q[1] += v.y * v.y; q[2] += v.z * v.z; q[3] += v.w * v.w;
    }
    #pragma unroll
    for (int i = 0; i < 4; i++) {
        #pragma unroll
        for (int off = 32; off >= 8; off >>= 1) {
            s[i] += __shfl_down(s[i], off, 64);
            q[i] += __shfl_down(q[i], off, 64);
        }
    }
    __shared__ float red[4][64];
    int wv = t >> 6, lane = t & 63;
    if (lane < 8) {   // lane == g for these lanes
        #pragma unroll
        for (int i = 0; i < 4; i++) {
            red[wv][lane * 4 + i] = s[i];
            red[wv][32 + lane * 4 + i] = q[i];
        }
    }
    __syncthreads();
    if (t < 64)
        partials[(size_t)blockIdx.x * 64 + t] =
            red[0][t] + red[1][t] + red[2][t] + red[3][t];
}

// ---------------------------------------------------------------------------
// Parallel reduce: block c handles channel c
// ---------------------------------------------------------------------------
__global__ __launch_bounds__(256) void k_reduce(
    const float* __restrict__ partials,
    const float* __restrict__ g, const float* __restrict__ b,
    float* __restrict__ stats_out)
{
    int c = blockIdx.x;
    int t = threadIdx.x;
    int part = t >> 7;
    int i0 = t & 127;
    float s = 0.f;
    for (int i = i0; i < COLS_BLOCKS; i += 128)
        s += partials[(size_t)i * 64 + part * 32 + c];
    __shared__ float sh[256];
    sh[t] = s;
    __syncthreads();
    #pragma unroll
    for (int off = 64; off; off >>= 1) {
        if ((t & 127) < off) sh[t] += sh[t + off];
        __syncthreads();
    }
    if (t == 0) {
        float S = sh[0], Q = sh[128];
        float mu = S * (1.f / N_PTS);
        float var = Q * (1.f / N_PTS) - mu * mu;
        float a = g[c] * rsqrtf(var + 1e-5f);
        stats_out[c] = a;
        stats_out[32 + c] = b[c] - mu * a;
    }
}

// ---------------------------------------------------------------------------
// Fused head. 512 threads = 8 waves; 128 points.
// Phase 1 (all threads): pt = t&127, quarter qd = t>>7 computes 4 mf chans,
// writes bf16 directly into zlds via 16-bit stores.
// Phase 2: wave = (slab = wv&1, pq = wv>>1); 16 p-iters of 4 MFMA + epilogue.
// ---------------------------------------------------------------------------
__global__ __launch_bounds__(512) void k_head(
    const float* __restrict__ ybuf, const float* __restrict__ coords,
    const float* __restrict__ w_out, const float* __restrict__ b_out,
    const float* __restrict__ stats, const float* __restrict__ w2p,
    const float* __restrict__ b2p, const float* __restrict__ apackf,
    float* __restrict__ out)
{
    __shared__ unsigned int zlds[HPB * 20];   // 80B per point
    unsigned short* zlds16 = (unsigned short*)zlds;
    int t = threadIdx.x;
    int nblk = blockIdx.x * HPB;

    // ---- phase 1 ----
    {
        int pt = t & 127, qd = t >> 7;        // qd in 0..3
        int nc = nblk + pt;
        if (nc >= N_PTS) nc = N_PTS - 1;
        const float* yr = ybuf + (size_t)nc * M;
        float x[M];
        #pragma unroll
        for (int q = 0; q < M / 4; q++) {
            float4 v = ((const float4*)yr)[q];
            x[4*q] = v.x; x[4*q+1] = v.y; x[4*q+2] = v.z; x[4*q+3] = v.w;
        }
        const float* st = stats + 128;
        #pragma unroll
        for (int j = 0; j < M; j++) x[j] = fmaxf(fmaf(x[j], st[j], st[32 + j]), 0.f);

        float mf[4];
        #pragma unroll
        for (int d = 0; d < 4; d++) mf[d] = b_out[qd * 4 + d];
        #pragma unroll
        for (int i = 0; i < M; i++) {
            float xi = x[i];
            #pragma unroll
            for (int d = 0; d < 4; d++) mf[d] = fmaf(xi, w_out[i * D + qd * 4 + d], mf[d]);
        }
        unsigned short* zp = zlds16 + pt * 40;
        #pragma unroll
        for (int d = 0; d < 4; d++) zp[3 + qd * 4 + d] = f2bf(mf[d]);
        if (qd == 0) {
            zp[0] = f2bf(coords[(size_t)nc * 3 + 0]);
            zp[1] = f2bf(coords[(size_t)nc * 3 + 1]);
            zp[2] = f2bf(coords[(size_t)nc * 3 + 2]);
            zp[19] = 0x3F80;   // bf16(1.0)
        } else if (qd == 3) {
            unsigned int* zw = (unsigned int*)(zp + 20);
            #pragma unroll
            for (int i = 0; i < 10; i++) zw[i] = 0u;
        }
    }
    __syncthreads();

    // ---- phase 2 ----
    int lane = t & 63, wv = t >> 6;
    int slab = wv & 1, pq = wv >> 1;          // pq in 0..3 -> p = pq*16 + i
    int cl = lane & 15, kg = lane >> 4;
    int n0 = nblk + slab * 64;
    int nn = n0 + lane;
    bool wr = nn < N_PTS;

    short8v b8[4];
    #pragma unroll
    for (int s = 0; s < 4; s++)
        b8[s] = *(const short8v*)&zlds[(slab * 64 + s * 16 + cl) * 20 + kg * 4];

    const char* abase = (const char*)apackf + (size_t)(pq * 16) * 1024 + lane * 16;
    float* outb = out + (size_t)(pq * 16) * N_PTS + nn;

    #pragma unroll 4
    for (int i = 0; i < 16; i++) {
        int p = pq * 16 + i;
        short8v a8 = *(const short8v*)(abase + (size_t)i * 1024);
        floatx4 w2v = *(const floatx4*)(w2p + p * 16 + kg * 4);
        float b2 = b2p[p];

        float vs[4];
        #pragma unroll
        for (int s = 0; s < 4; s++) {
            floatx4 acc = {0.f, 0.f, 0.f, 0.f};
            acc = __builtin_amdgcn_mfma_f32_16x16x32_bf16(a8, b8[s], acc, 0, 0, 0);
            float m01 = fmaxf(acc[0], 0.f) * w2v[0];
            m01 = fmaf(fmaxf(acc[1], 0.f), w2v[1], m01);
            float m23 = fmaxf(acc[2], 0.f) * w2v[2];
            m23 = fmaf(fmaxf(acc[3], 0.f), w2v[3], m23);
            float v = m01 + m23;
            v += __shfl_xor(v, 16, 64);
            v += __shfl_xor(v, 32, 64);
            vs[s] = v;
        }
        float vout = (kg == 0) ? vs[0] : (kg == 1) ? vs[1] : (kg == 2) ? vs[2] : vs[3];
        if (wr) outb[(size_t)i * N_PTS] = vout + b2;
    }
}

// ---------------------------------------------------------------------------
extern "C" void kernel_launch(void* const* d_in, const int* in_sizes, int n_in,
                              void* d_out, int out_size, void* d_ws, size_t ws_size,
                              hipStream_t stream) {
    const float* feats   = (const float*)d_in[0];
    const float* coords  = (const float*)d_in[1];
    const float* inst    = (const float*)d_in[2];
    const float* centers = (const float*)d_in[3];
    const float* mw1 = (const float*)d_in[4];
    const float* mg1 = (const float*)d_in[5];
    const float* mb1 = (const float*)d_in[6];
    const float* mw2 = (const float*)d_in[7];
    const float* mg2 = (const float*)d_in[8];
    const float* mb2 = (const float*)d_in[9];
    const float* mw3 = (const float*)d_in[10];
    const float* mg3 = (const float*)d_in[11];
    const float* mb3 = (const float*)d_in[12];
    const float* wout = (const float*)d_in[13];
    const float* bout = (const float*)d_in[14];
    const float* embw = (const float*)d_in[15];
    const float* embg = (const float*)d_in[16];
    const float* embb = (const float*)d_in[17];
    const float* cw   = (const float*)d_in[18];
    const float* cb   = (const float*)d_in[19];

    float* wsf      = (float*)d_ws;
    float* params   = wsf + WS_PARAMS;
    float* stats    = wsf + WS_STATS;
    float* w2p      = wsf + WS_W2;
    float* b2p      = wsf + WS_B2;
    float* apackf   = wsf + WS_APACK;
    float* ybuf     = wsf + WS_Y;
    float* out      = (float*)d_out;
    float* partials = (float*)d_out;   // scratch until k_head overwrites out

    k_params<<<1, 256, 0, stream>>>(inst, embw, embg, embb, cw, cb, params);
    k_pack<<<P_INST, 64, 0, stream>>>(params, centers, apackf, w2p, b2p);

    k_layer<0><<<NBL, 256, 0, stream>>>(feats, mw1, stats, ybuf);
    k_colsum<<<COLS_BLOCKS, 256, 0, stream>>>(ybuf, partials);
    k_reduce<<<32, 256, 0, stream>>>(partials, mg1, mb1, stats + 0);

    k_layer<1><<<NBL, 256, 0, stream>>>(feats, mw2, stats, ybuf);
    k_colsum<<<COLS_BLOCKS, 256, 0, stream>>>(ybuf, partials);
    k_reduce<<<32, 256, 0, stream>>>(partials, mg2, mb2, stats + 64);

    k_layer<2><<<NBL, 256, 0, stream>>>(feats, mw3, stats, ybuf);
    k_colsum<<<COLS_BLOCKS, 256, 0, stream>>>(ybuf, partials);
    k_reduce<<<32, 256, 0, stream>>>(partials, mg3, mb3, stats + 128);

    k_head<<<NBH, 512, 0, stream>>>(ybuf, coords, wout, bout, stats,
                                    w2p, b2p, apackf, out);
}

// Round 8
// 182.453 us; speedup vs baseline: 1.2081x; 1.0446x over previous
//
#include <hip/hip_runtime.h>
#include <hip/hip_bf16.h>
#include <math.h>

#define N_PTS 200000
#define M 32
#define P_INST 64
#define D 16
#define NP 337

#define NBL ((N_PTS + 255) / 256)      // 782 layer blocks (256 pts each)
#define HPB 128                        // points per head block
#define NBH ((N_PTS + HPB - 1) / HPB)  // 1563

// ws float-offset layout:
#define WS_PARAMS 0         // 64*337 = 21568
#define WS_STATS  21568     // 3*64 (per layer: a[32], c[32])
#define WS_W2     21760     // 64*16
#define WS_B2     22784     // 64
#define WS_APACK  22912     // 64*512 bf16 = 16384 float-slots
#define WS_Y      104832    // 200000*32 floats (25.6MB)
// partials[NBL][64] live in d_out (scratch until k_head overwrites)

typedef __attribute__((ext_vector_type(8))) short short8v;
typedef __attribute__((ext_vector_type(4))) float floatx4;

static __device__ __forceinline__ unsigned short f2bf(float v) {
    __hip_bfloat16 h = __float2bfloat16(v);
    return *reinterpret_cast<unsigned short*>(&h);
}

// ---------------------------------------------------------------------------
// k_prep: embedding MLP + BN(64) + controller -> params (global), fence,
// then pack A-frags (bf16, centers folded into bias K-row), w2, b2.
// One block of 256.  (R3-verified pattern.)
// ---------------------------------------------------------------------------
__global__ __launch_bounds__(256) void k_prep(
    const float* __restrict__ inst, const float* __restrict__ emb_w,
    const float* __restrict__ emb_g, const float* __restrict__ emb_b,
    const float* __restrict__ ctrl_w, const float* __restrict__ ctrl_b,
    const float* __restrict__ centers,
    float* __restrict__ params, float* __restrict__ apackf,
    float* __restrict__ w2p, float* __restrict__ b2p)
{
    __shared__ float sInst[P_INST * M];
    __shared__ float sE[P_INST * D];
    __shared__ float sCW[D * NP];
    __shared__ float sA[D], sC[D];
    int t = threadIdx.x;

    for (int i = t; i < P_INST * M; i += 256) sInst[i] = inst[i];
    for (int i = t; i < D * NP; i += 256) sCW[i] = ctrl_w[i];
    __syncthreads();

    for (int i = t; i < P_INST * D; i += 256) {
        int p = i >> 4, d = i & (D - 1);
        float acc = 0.f;
        #pragma unroll
        for (int k = 0; k < M; k++) acc = fmaf(sInst[p * M + k], emb_w[k * D + d], acc);
        sE[i] = acc;
    }
    __syncthreads();

    if (t < D) {
        float s = 0.f, q = 0.f;
        for (int p = 0; p < P_INST; p++) { float v = sE[p * D + t]; s += v; q += v * v; }
        float mu = s * (1.f / P_INST);
        float var = q * (1.f / P_INST) - mu * mu;
        float a = emb_g[t] * rsqrtf(var + 1e-5f);
        sA[t] = a;
        sC[t] = emb_b[t] - mu * a;
    }
    __syncthreads();

    for (int i = t; i < P_INST * D; i += 256) {
        int d = i & (D - 1);
        sE[i] = fmaxf(sE[i] * sA[d] + sC[d], 0.f);
    }
    __syncthreads();

    for (int i = t; i < P_INST * NP; i += 256) {
        int p = i / NP, q = i - p * NP;
        float acc = ctrl_b[q];
        #pragma unroll
        for (int d = 0; d < D; d++) acc = fmaf(sE[p * D + d], sCW[d * NP + q], acc);
        params[i] = acc;
    }
    __threadfence_block();
    __syncthreads();

    // pack phase: wave wv handles p = wv, wv+4, ...
    int lane = t & 63, wv = t >> 6;
    int row = lane & 15, kbase = (lane >> 4) * 8;
    for (int p = wv; p < P_INST; p += 4) {
        const float* pp = params + p * NP;
        unsigned int w[4];
        #pragma unroll
        for (int i = 0; i < 4; i++) {
            unsigned short lo = 0, hi = 0;
            #pragma unroll
            for (int h = 0; h < 2; h++) {
                int k = kbase + 2 * i + h;
                float v;
                if (k < 19) v = pp[row * 19 + k];
                else if (k == 19)
                    v = pp[320 + row] - (centers[p * 3 + 0] * pp[row * 19 + 0]
                                       + centers[p * 3 + 1] * pp[row * 19 + 1]
                                       + centers[p * 3 + 2] * pp[row * 19 + 2]);
                else v = 0.f;
                if (h == 0) lo = f2bf(v); else hi = f2bf(v);
            }
            w[i] = (unsigned)lo | ((unsigned)hi << 16);
        }
        uint4* dst = (uint4*)((char*)apackf + (size_t)p * 1024 + lane * 16);
        *dst = make_uint4(w[0], w[1], w[2], w[3]);

        if (lane < 16) w2p[p * 16 + lane] = pp[304 + lane];
        if (lane == 0) b2p[p] = pp[336];
    }
}

// ---------------------------------------------------------------------------
// MLP layer + fused stats. 256 pts/block, full 32 channels per thread
// (W indices compile-time -> s_load), then LDS-transpose block reduction.
// (R4-verified pattern.)
// ---------------------------------------------------------------------------
template <int L>
__global__ __launch_bounds__(256) void k_layer(
    const float* __restrict__ feats, const float* __restrict__ W,
    const float* __restrict__ stats, float* __restrict__ ybuf,
    float* __restrict__ partials)
{
    __shared__ float tr[256 * 33];
    __shared__ float red2[2][8][32];
    int t = threadIdx.x;
    int n = blockIdx.x * 256 + t;
    bool valid = n < N_PTS;
    int nc = valid ? n : N_PTS - 1;

    const float* src = ((L == 0) ? feats : ybuf) + (size_t)nc * M;
    float x[M];
    #pragma unroll
    for (int q = 0; q < M / 4; q++) {
        float4 v = ((const float4*)src)[q];
        x[4*q] = v.x; x[4*q+1] = v.y; x[4*q+2] = v.z; x[4*q+3] = v.w;
    }
    if (L > 0) {
        const float* st = stats + (L - 1) * 64;
        #pragma unroll
        for (int j = 0; j < M; j++) x[j] = fmaxf(fmaf(x[j], st[j], st[32 + j]), 0.f);
    }
    float y[M];
    #pragma unroll
    for (int j = 0; j < M; j++) y[j] = 0.f;
    #pragma unroll
    for (int i = 0; i < M; i++) {
        float xi = x[i];
        #pragma unroll
        for (int j = 0; j < M; j++) y[j] = fmaf(xi, W[i * M + j], y[j]);
    }
    if (valid) {
        float4* dst = (float4*)(ybuf + (size_t)n * M);
        #pragma unroll
        for (int q = 0; q < M / 4; q++)
            dst[q] = make_float4(y[4*q], y[4*q+1], y[4*q+2], y[4*q+3]);
    } else {
        #pragma unroll
        for (int j = 0; j < M; j++) y[j] = 0.f;
    }

    #pragma unroll
    for (int j = 0; j < M; j++) tr[t * 33 + j] = y[j];
    __syncthreads();
    int c = t & 31, s = t >> 5;
    float S = 0.f, Q = 0.f;
    #pragma unroll
    for (int r = 0; r < 32; r++) {
        float v = tr[(s * 32 + r) * 33 + c];
        S += v; Q += v * v;
    }
    red2[0][s][c] = S;
    red2[1][s][c] = Q;
    __syncthreads();
    if (t < 64) {
        int cc = t & 31, k = t >> 5;
        float a = 0.f;
        #pragma unroll
        for (int sl = 0; sl < 8; sl++) a += red2[k][sl][cc];
        partials[(size_t)blockIdx.x * 64 + k * 32 + cc] = a;
    }
}

// ---------------------------------------------------------------------------
// Parallel reduce: block c handles channel c
// ---------------------------------------------------------------------------
__global__ __launch_bounds__(256) void k_reduce(
    const float* __restrict__ partials,
    const float* __restrict__ g, const float* __restrict__ b,
    float* __restrict__ stats_out)
{
    int c = blockIdx.x;
    int t = threadIdx.x;
    int part = t >> 7;
    int i0 = t & 127;
    float s = 0.f;
    for (int i = i0; i < NBL; i += 128)
        s += partials[(size_t)i * 64 + part * 32 + c];
    __shared__ float sh[256];
    sh[t] = s;
    __syncthreads();
    #pragma unroll
    for (int off = 64; off; off >>= 1) {
        if ((t & 127) < off) sh[t] += sh[t + off];
        __syncthreads();
    }
    if (t == 0) {
        float S = sh[0], Q = sh[128];
        float mu = S * (1.f / N_PTS);
        float var = Q * (1.f / N_PTS) - mu * mu;
        float a = g[c] * rsqrtf(var + 1e-5f);
        stats_out[c] = a;
        stats_out[32 + c] = b[c] - mu * a;
    }
}

// ---------------------------------------------------------------------------
// Fused head. 512 threads = 8 waves; 128 points.
// Phase 1: thread (pt = t&127, qd = t>>7) computes 4 mf channels -> zlds.
// Phase 2: wave (slab = wv&1, pq = wv>>1): 16 p-iters of 4 MFMA + shfl
// epilogue (R6-verified). __launch_bounds__(512,2) gives the RA ~128 VGPRs
// so b8[4] stays resident and a8 prefetch pipelines (R6 had VGPR=32 ->
// per-iter ds_read remat + serialization).
// ---------------------------------------------------------------------------
__global__ __launch_bounds__(512, 2) void k_head(
    const float* __restrict__ ybuf, const float* __restrict__ coords,
    const float* __restrict__ w_out, const float* __restrict__ b_out,
    const float* __restrict__ stats, const float* __restrict__ w2p,
    const float* __restrict__ b2p, const float* __restrict__ apackf,
    float* __restrict__ out)
{
    __shared__ unsigned int zlds[HPB * 20];   // 80B per point
    unsigned short* zlds16 = (unsigned short*)zlds;
    int t = threadIdx.x;
    int nblk = blockIdx.x * HPB;

    // ---- phase 1 ----
    {
        int pt = t & 127, qd = t >> 7;        // qd in 0..3
        int nc = nblk + pt;
        if (nc >= N_PTS) nc = N_PTS - 1;
        const float* yr = ybuf + (size_t)nc * M;
        float x[M];
        #pragma unroll
        for (int q = 0; q < M / 4; q++) {
            float4 v = ((const float4*)yr)[q];
            x[4*q] = v.x; x[4*q+1] = v.y; x[4*q+2] = v.z; x[4*q+3] = v.w;
        }
        const float* st = stats + 128;
        #pragma unroll
        for (int j = 0; j < M; j++) x[j] = fmaxf(fmaf(x[j], st[j], st[32 + j]), 0.f);

        float mf[4];
        #pragma unroll
        for (int d = 0; d < 4; d++) mf[d] = b_out[qd * 4 + d];
        #pragma unroll
        for (int i = 0; i < M; i++) {
            float xi = x[i];
            #pragma unroll
            for (int d = 0; d < 4; d++) mf[d] = fmaf(xi, w_out[i * D + qd * 4 + d], mf[d]);
        }
        unsigned short* zp = zlds16 + pt * 40;
        #pragma unroll
        for (int d = 0; d < 4; d++) zp[3 + qd * 4 + d] = f2bf(mf[d]);
        if (qd == 0) {
            zp[0] = f2bf(coords[(size_t)nc * 3 + 0]);
            zp[1] = f2bf(coords[(size_t)nc * 3 + 1]);
            zp[2] = f2bf(coords[(size_t)nc * 3 + 2]);
            zp[19] = 0x3F80;   // bf16(1.0)
        } else if (qd == 3) {
            unsigned int* zw = (unsigned int*)(zp + 20);
            #pragma unroll
            for (int i = 0; i < 10; i++) zw[i] = 0u;
        }
    }
    __syncthreads();

    // ---- phase 2 ----
    int lane = t & 63, wv = t >> 6;
    int slab = wv & 1, pq = wv >> 1;          // pq in 0..3 -> p = pq*16 + i
    int cl = lane & 15, kg = lane >> 4;
    int n0 = nblk + slab * 64;
    int nn = n0 + lane;
    bool wr = nn < N_PTS;

    short8v b8[4];
    #pragma unroll
    for (int s = 0; s < 4; s++)
        b8[s] = *(const short8v*)&zlds[(slab * 64 + s * 16 + cl) * 20 + kg * 4];

    const char* abase = (const char*)apackf + (size_t)(pq * 16) * 1024 + lane * 16;
    float* outb = out + (size_t)(pq * 16) * N_PTS + nn;

    // one-ahead prefetch of the A fragment
    short8v a8n = *(const short8v*)abase;

    #pragma unroll 4
    for (int i = 0; i < 16; i++) {
        int p = pq * 16 + i;
        short8v a8 = a8n;
        if (i < 15) a8n = *(const short8v*)(abase + (size_t)(i + 1) * 1024);
        floatx4 w2v = *(const floatx4*)(w2p + p * 16 + kg * 4);
        float b2 = b2p[p];

        float vs[4];
        #pragma unroll
        for (int s = 0; s < 4; s++) {
            floatx4 acc = {0.f, 0.f, 0.f, 0.f};
            acc = __builtin_amdgcn_mfma_f32_16x16x32_bf16(a8, b8[s], acc, 0, 0, 0);
            float m01 = fmaxf(acc[0], 0.f) * w2v[0];
            m01 = fmaf(fmaxf(acc[1], 0.f), w2v[1], m01);
            float m23 = fmaxf(acc[2], 0.f) * w2v[2];
            m23 = fmaf(fmaxf(acc[3], 0.f), w2v[3], m23);
            float v = m01 + m23;
            v += __shfl_xor(v, 16, 64);
            v += __shfl_xor(v, 32, 64);
            vs[s] = v;
        }
        float vout = (kg == 0) ? vs[0] : (kg == 1) ? vs[1] : (kg == 2) ? vs[2] : vs[3];
        if (wr) outb[(size_t)i * N_PTS] = vout + b2;
    }
}

// ---------------------------------------------------------------------------
extern "C" void kernel_launch(void* const* d_in, const int* in_sizes, int n_in,
                              void* d_out, int out_size, void* d_ws, size_t ws_size,
                              hipStream_t stream) {
    const float* feats   = (const float*)d_in[0];
    const float* coords  = (const float*)d_in[1];
    const float* inst    = (const float*)d_in[2];
    const float* centers = (const float*)d_in[3];
    const float* mw1 = (const float*)d_in[4];
    const float* mg1 = (const float*)d_in[5];
    const float* mb1 = (const float*)d_in[6];
    const float* mw2 = (const float*)d_in[7];
    const float* mg2 = (const float*)d_in[8];
    const float* mb2 = (const float*)d_in[9];
    const float* mw3 = (const float*)d_in[10];
    const float* mg3 = (const float*)d_in[11];
    const float* mb3 = (const float*)d_in[12];
    const float* wout = (const float*)d_in[13];
    const float* bout = (const float*)d_in[14];
    const float* embw = (const float*)d_in[15];
    const float* embg = (const float*)d_in[16];
    const float* embb = (const float*)d_in[17];
    const float* cw   = (const float*)d_in[18];
    const float* cb   = (const float*)d_in[19];

    float* wsf      = (float*)d_ws;
    float* params   = wsf + WS_PARAMS;
    float* stats    = wsf + WS_STATS;
    float* w2p      = wsf + WS_W2;
    float* b2p      = wsf + WS_B2;
    float* apackf   = wsf + WS_APACK;
    float* ybuf     = wsf + WS_Y;
    float* out      = (float*)d_out;
    float* partials = (float*)d_out;   // scratch until k_head overwrites out

    k_prep<<<1, 256, 0, stream>>>(inst, embw, embg, embb, cw, cb, centers,
                                  params, apackf, w2p, b2p);

    k_layer<0><<<NBL, 256, 0, stream>>>(feats, mw1, stats, ybuf, partials);
    k_reduce<<<32, 256, 0, stream>>>(partials, mg1, mb1, stats + 0);

    k_layer<1><<<NBL, 256, 0, stream>>>(feats, mw2, stats, ybuf, partials);
    k_reduce<<<32, 256, 0, stream>>>(partials, mg2, mb2, stats + 64);

    k_layer<2><<<NBL, 256, 0, stream>>>(feats, mw3, stats, ybuf, partials);
    k_reduce<<<32, 256, 0, stream>>>(partials, mg3, mb3, stats + 128);

    k_head<<<NBH, 512, 0, stream>>>(ybuf, coords, wout, bout, stats,
                                    w2p, b2p, apackf, out);
}

// Round 9
// 158.758 us; speedup vs baseline: 1.3885x; 1.1493x over previous
//
#include <hip/hip_runtime.h>
#include <hip/hip_bf16.h>
#include <math.h>

#define N_PTS 200000
#define M 32
#define P_INST 64
#define D 16
#define NP 337

#define NBL ((N_PTS + 255) / 256)      // 782 layer blocks (256 pts each)
#define HPB 128                        // points per head block
#define NBH ((N_PTS + HPB - 1) / HPB)  // 1563

// ws float-offset layout:
#define WS_PARAMS 0         // 64*337 = 21568
#define WS_STATS  21568     // 3*64 (per layer: a[32], c[32])
#define WS_W2     21760     // 64*16
#define WS_B2     22784     // 64
#define WS_APACK  22912     // 64*512 bf16 = 16384 float-slots
#define WS_Y      104832    // 200000*32 floats (25.6MB)
// partials[NBL][64] live in d_out (scratch until k_head overwrites)

typedef __attribute__((ext_vector_type(8))) short short8v;
typedef __attribute__((ext_vector_type(4))) float floatx4;

static __device__ __forceinline__ unsigned short f2bf(float v) {
    __hip_bfloat16 h = __float2bfloat16(v);
    return *reinterpret_cast<unsigned short*>(&h);
}

// ---------------------------------------------------------------------------
// k_prep: embedding MLP + BN(64) + controller -> params (global), fence,
// then pack A-frags (bf16, centers folded into bias K-row), w2, b2.
// 1024 threads = 16 waves (4/SIMD) so latency chains overlap; no integer
// division (wave-structured controller layout).
// ---------------------------------------------------------------------------
__global__ __launch_bounds__(1024) void k_prep(
    const float* __restrict__ inst, const float* __restrict__ emb_w,
    const float* __restrict__ emb_g, const float* __restrict__ emb_b,
    const float* __restrict__ ctrl_w, const float* __restrict__ ctrl_b,
    const float* __restrict__ centers,
    float* __restrict__ params, float* __restrict__ apackf,
    float* __restrict__ w2p, float* __restrict__ b2p)
{
    __shared__ float sInst[P_INST * M];   // 8 KB
    __shared__ float sCW[D * NP];         // 21.6 KB
    __shared__ float sE[P_INST * D];      // 4 KB
    __shared__ float sA[D], sC[D];
    int t = threadIdx.x;
    int lane = t & 63, wv = t >> 6;       // wv in 0..15

    for (int i = t; i < P_INST * M; i += 1024) sInst[i] = inst[i];
    for (int i = t; i < D * NP; i += 1024) sCW[i] = ctrl_w[i];
    __syncthreads();

    // emb = inst @ emb_w : exactly one output per thread
    {
        int p = t >> 4, d = t & (D - 1);
        float acc = 0.f;
        #pragma unroll
        for (int k = 0; k < M; k++) acc = fmaf(sInst[p * M + k], emb_w[k * D + d], acc);
        sE[t] = acc;                      // sE[p*16 + d]
    }
    __syncthreads();

    // BN over 64 rows, per column d (16 threads, short serial loop)
    if (t < D) {
        float s = 0.f, q = 0.f;
        for (int p = 0; p < P_INST; p++) { float v = sE[p * D + t]; s += v; q += v * v; }
        float mu = s * (1.f / P_INST);
        float var = q * (1.f / P_INST) - mu * mu;
        float a = emb_g[t] * rsqrtf(var + 1e-5f);
        sA[t] = a;
        sC[t] = emb_b[t] - mu * a;
    }
    __syncthreads();

    // relu(bn(.)): one element per thread
    {
        int d = t & (D - 1);
        sE[t] = fmaxf(sE[t] * sA[d] + sC[d], 0.f);
    }
    __syncthreads();

    // controller: wave wv owns p = wv*4 + pp (wave-uniform); lanes stride q.
    #pragma unroll
    for (int pp = 0; pp < 4; pp++) {
        int p = wv * 4 + pp;
        float e[D];
        #pragma unroll
        for (int d = 0; d < D; d++) e[d] = sE[p * D + d];   // broadcast LDS reads
        for (int q = lane; q < NP; q += 64) {
            float acc = ctrl_b[q];
            #pragma unroll
            for (int d = 0; d < D; d++) acc = fmaf(e[d], sCW[d * NP + q], acc);
            params[p * NP + q] = acc;
        }
    }
    __threadfence_block();
    __syncthreads();

    // pack phase: wave wv packs p = wv, wv+16, wv+32, wv+48
    int row = lane & 15, kbase = (lane >> 4) * 8;
    #pragma unroll
    for (int pi = 0; pi < 4; pi++) {
        int p = wv + pi * 16;
        const float* pp = params + p * NP;
        unsigned int w[4];
        #pragma unroll
        for (int i = 0; i < 4; i++) {
            unsigned short lo = 0, hi = 0;
            #pragma unroll
            for (int h = 0; h < 2; h++) {
                int k = kbase + 2 * i + h;
                float v;
                if (k < 19) v = pp[row * 19 + k];
                else if (k == 19)
                    v = pp[320 + row] - (centers[p * 3 + 0] * pp[row * 19 + 0]
                                       + centers[p * 3 + 1] * pp[row * 19 + 1]
                                       + centers[p * 3 + 2] * pp[row * 19 + 2]);
                else v = 0.f;
                if (h == 0) lo = f2bf(v); else hi = f2bf(v);
            }
            w[i] = (unsigned)lo | ((unsigned)hi << 16);
        }
        uint4* dst = (uint4*)((char*)apackf + (size_t)p * 1024 + lane * 16);
        *dst = make_uint4(w[0], w[1], w[2], w[3]);

        if (lane < 16) w2p[p * 16 + lane] = pp[304 + lane];
        if (lane == 0) b2p[p] = pp[336];
    }
}

// ---------------------------------------------------------------------------
// MLP layer + fused stats. 256 pts/block, full 32 channels per thread
// (W indices compile-time -> s_load), then LDS-transpose block reduction.
// ---------------------------------------------------------------------------
template <int L>
__global__ __launch_bounds__(256) void k_layer(
    const float* __restrict__ feats, const float* __restrict__ W,
    const float* __restrict__ stats, float* __restrict__ ybuf,
    float* __restrict__ partials)
{
    __shared__ float tr[256 * 33];
    __shared__ float red2[2][8][32];
    int t = threadIdx.x;
    int n = blockIdx.x * 256 + t;
    bool valid = n < N_PTS;
    int nc = valid ? n : N_PTS - 1;

    const float* src = ((L == 0) ? feats : ybuf) + (size_t)nc * M;
    float x[M];
    #pragma unroll
    for (int q = 0; q < M / 4; q++) {
        float4 v = ((const float4*)src)[q];
        x[4*q] = v.x; x[4*q+1] = v.y; x[4*q+2] = v.z; x[4*q+3] = v.w;
    }
    if (L > 0) {
        const float* st = stats + (L - 1) * 64;
        #pragma unroll
        for (int j = 0; j < M; j++) x[j] = fmaxf(fmaf(x[j], st[j], st[32 + j]), 0.f);
    }
    float y[M];
    #pragma unroll
    for (int j = 0; j < M; j++) y[j] = 0.f;
    #pragma unroll
    for (int i = 0; i < M; i++) {
        float xi = x[i];
        #pragma unroll
        for (int j = 0; j < M; j++) y[j] = fmaf(xi, W[i * M + j], y[j]);
    }
    if (valid) {
        float4* dst = (float4*)(ybuf + (size_t)n * M);
        #pragma unroll
        for (int q = 0; q < M / 4; q++)
            dst[q] = make_float4(y[4*q], y[4*q+1], y[4*q+2], y[4*q+3]);
    } else {
        #pragma unroll
        for (int j = 0; j < M; j++) y[j] = 0.f;
    }

    #pragma unroll
    for (int j = 0; j < M; j++) tr[t * 33 + j] = y[j];
    __syncthreads();
    int c = t & 31, s = t >> 5;
    float S = 0.f, Q = 0.f;
    #pragma unroll
    for (int r = 0; r < 32; r++) {
        float v = tr[(s * 32 + r) * 33 + c];
        S += v; Q += v * v;
    }
    red2[0][s][c] = S;
    red2[1][s][c] = Q;
    __syncthreads();
    if (t < 64) {
        int cc = t & 31, k = t >> 5;
        float a = 0.f;
        #pragma unroll
        for (int sl = 0; sl < 8; sl++) a += red2[k][sl][cc];
        partials[(size_t)blockIdx.x * 64 + k * 32 + cc] = a;
    }
}

// ---------------------------------------------------------------------------
// Parallel reduce: block c handles channel c
// ---------------------------------------------------------------------------
__global__ __launch_bounds__(256) void k_reduce(
    const float* __restrict__ partials,
    const float* __restrict__ g, const float* __restrict__ b,
    float* __restrict__ stats_out)
{
    int c = blockIdx.x;
    int t = threadIdx.x;
    int part = t >> 7;
    int i0 = t & 127;
    float s = 0.f;
    for (int i = i0; i < NBL; i += 128)
        s += partials[(size_t)i * 64 + part * 32 + c];
    __shared__ float sh[256];
    sh[t] = s;
    __syncthreads();
    #pragma unroll
    for (int off = 64; off; off >>= 1) {
        if ((t & 127) < off) sh[t] += sh[t + off];
        __syncthreads();
    }
    if (t == 0) {
        float S = sh[0], Q = sh[128];
        float mu = S * (1.f / N_PTS);
        float var = Q * (1.f / N_PTS) - mu * mu;
        float a = g[c] * rsqrtf(var + 1e-5f);
        stats_out[c] = a;
        stats_out[32 + c] = b[c] - mu * a;
    }
}

// ---------------------------------------------------------------------------
// Fused head. 512 threads = 8 waves; 128 points. (unchanged from R8)
// ---------------------------------------------------------------------------
__global__ __launch_bounds__(512, 2) void k_head(
    const float* __restrict__ ybuf, const float* __restrict__ coords,
    const float* __restrict__ w_out, const float* __restrict__ b_out,
    const float* __restrict__ stats, const float* __restrict__ w2p,
    const float* __restrict__ b2p, const float* __restrict__ apackf,
    float* __restrict__ out)
{
    __shared__ unsigned int zlds[HPB * 20];   // 80B per point
    unsigned short* zlds16 = (unsigned short*)zlds;
    int t = threadIdx.x;
    int nblk = blockIdx.x * HPB;

    // ---- phase 1 ----
    {
        int pt = t & 127, qd = t >> 7;        // qd in 0..3
        int nc = nblk + pt;
        if (nc >= N_PTS) nc = N_PTS - 1;
        const float* yr = ybuf + (size_t)nc * M;
        float x[M];
        #pragma unroll
        for (int q = 0; q < M / 4; q++) {
            float4 v = ((const float4*)yr)[q];
            x[4*q] = v.x; x[4*q+1] = v.y; x[4*q+2] = v.z; x[4*q+3] = v.w;
        }
        const float* st = stats + 128;
        #pragma unroll
        for (int j = 0; j < M; j++) x[j] = fmaxf(fmaf(x[j], st[j], st[32 + j]), 0.f);

        float mf[4];
        #pragma unroll
        for (int d = 0; d < 4; d++) mf[d] = b_out[qd * 4 + d];
        #pragma unroll
        for (int i = 0; i < M; i++) {
            float xi = x[i];
            #pragma unroll
            for (int d = 0; d < 4; d++) mf[d] = fmaf(xi, w_out[i * D + qd * 4 + d], mf[d]);
        }
        unsigned short* zp = zlds16 + pt * 40;
        #pragma unroll
        for (int d = 0; d < 4; d++) zp[3 + qd * 4 + d] = f2bf(mf[d]);
        if (qd == 0) {
            zp[0] = f2bf(coords[(size_t)nc * 3 + 0]);
            zp[1] = f2bf(coords[(size_t)nc * 3 + 1]);
            zp[2] = f2bf(coords[(size_t)nc * 3 + 2]);
            zp[19] = 0x3F80;   // bf16(1.0)
        } else if (qd == 3) {
            unsigned int* zw = (unsigned int*)(zp + 20);
            #pragma unroll
            for (int i = 0; i < 10; i++) zw[i] = 0u;
        }
    }
    __syncthreads();

    // ---- phase 2 ----
    int lane = t & 63, wv = t >> 6;
    int slab = wv & 1, pq = wv >> 1;          // pq in 0..3 -> p = pq*16 + i
    int cl = lane & 15, kg = lane >> 4;
    int n0 = nblk + slab * 64;
    int nn = n0 + lane;
    bool wr = nn < N_PTS;

    short8v b8[4];
    #pragma unroll
    for (int s = 0; s < 4; s++)
        b8[s] = *(const short8v*)&zlds[(slab * 64 + s * 16 + cl) * 20 + kg * 4];

    const char* abase = (const char*)apackf + (size_t)(pq * 16) * 1024 + lane * 16;
    float* outb = out + (size_t)(pq * 16) * N_PTS + nn;

    short8v a8n = *(const short8v*)abase;

    #pragma unroll 4
    for (int i = 0; i < 16; i++) {
        int p = pq * 16 + i;
        short8v a8 = a8n;
        if (i < 15) a8n = *(const short8v*)(abase + (size_t)(i + 1) * 1024);
        floatx4 w2v = *(const floatx4*)(w2p + p * 16 + kg * 4);
        float b2 = b2p[p];

        float vs[4];
        #pragma unroll
        for (int s = 0; s < 4; s++) {
            floatx4 acc = {0.f, 0.f, 0.f, 0.f};
            acc = __builtin_amdgcn_mfma_f32_16x16x32_bf16(a8, b8[s], acc, 0, 0, 0);
            float m01 = fmaxf(acc[0], 0.f) * w2v[0];
            m01 = fmaf(fmaxf(acc[1], 0.f), w2v[1], m01);
            float m23 = fmaxf(acc[2], 0.f) * w2v[2];
            m23 = fmaf(fmaxf(acc[3], 0.f), w2v[3], m23);
            float v = m01 + m23;
            v += __shfl_xor(v, 16, 64);
            v += __shfl_xor(v, 32, 64);
            vs[s] = v;
        }
        float vout = (kg == 0) ? vs[0] : (kg == 1) ? vs[1] : (kg == 2) ? vs[2] : vs[3];
        if (wr) outb[(size_t)i * N_PTS] = vout + b2;
    }
}

// ---------------------------------------------------------------------------
extern "C" void kernel_launch(void* const* d_in, const int* in_sizes, int n_in,
                              void* d_out, int out_size, void* d_ws, size_t ws_size,
                              hipStream_t stream) {
    const float* feats   = (const float*)d_in[0];
    const float* coords  = (const float*)d_in[1];
    const float* inst    = (const float*)d_in[2];
    const float* centers = (const float*)d_in[3];
    const float* mw1 = (const float*)d_in[4];
    const float* mg1 = (const float*)d_in[5];
    const float* mb1 = (const float*)d_in[6];
    const float* mw2 = (const float*)d_in[7];
    const float* mg2 = (const float*)d_in[8];
    const float* mb2 = (const float*)d_in[9];
    const float* mw3 = (const float*)d_in[10];
    const float* mg3 = (const float*)d_in[11];
    const float* mb3 = (const float*)d_in[12];
    const float* wout = (const float*)d_in[13];
    const float* bout = (const float*)d_in[14];
    const float* embw = (const float*)d_in[15];
    const float* embg = (const float*)d_in[16];
    const float* embb = (const float*)d_in[17];
    const float* cw   = (const float*)d_in[18];
    const float* cb   = (const float*)d_in[19];

    float* wsf      = (float*)d_ws;
    float* params   = wsf + WS_PARAMS;
    float* stats    = wsf + WS_STATS;
    float* w2p      = wsf + WS_W2;
    float* b2p      = wsf + WS_B2;
    float* apackf   = wsf + WS_APACK;
    float* ybuf     = wsf + WS_Y;
    float* out      = (float*)d_out;
    float* partials = (float*)d_out;   // scratch until k_head overwrites out

    k_prep<<<1, 1024, 0, stream>>>(inst, embw, embg, embb, cw, cb, centers,
                                   params, apackf, w2p, b2p);

    k_layer<0><<<NBL, 256, 0, stream>>>(feats, mw1, stats, ybuf, partials);
    k_reduce<<<32, 256, 0, stream>>>(partials, mg1, mb1, stats + 0);

    k_layer<1><<<NBL, 256, 0, stream>>>(feats, mw2, stats, ybuf, partials);
    k_reduce<<<32, 256, 0, stream>>>(partials, mg2, mb2, stats + 64);

    k_layer<2><<<NBL, 256, 0, stream>>>(feats, mw3, stats, ybuf, partials);
    k_reduce<<<32, 256, 0, stream>>>(partials, mg3, mb3, stats + 128);

    k_head<<<NBH, 512, 0, stream>>>(ybuf, coords, wout, bout, stats,
                                    w2p, b2p, apackf, out);
}